// Round 18
// baseline (113.510 us; speedup 1.0000x reference)
//
#include <hip/hip_runtime.h>
#include <hip/hip_cooperative_groups.h>

namespace cg = cooperative_groups;

// CRF-RNN collapsed: out[t,i] = sum_j M[i,j] * orig[t,j],
//   orig[t,j] = sum_m inputs[t,j,m]*W_feat[m]
//   M = (I + B + B^2 + B^3) * diag(1/denom) + B^4
// ONE cooperative dispatch (grid 256 = 1 block/CU, co-resident):
//   phase 1: block b -> B row b, Einv[b]          (k_prep body)
//   grid.sync()
//   phase 2: block b -> M row b (power chain)     (k_rows body)
//   phase 3a: stream 64-row input tile -> A LDS   (r16 stage-1)
//   grid.sync()   <- stragglers' phase 2 hidden under the 25us stream
//   phase 3b: 4 B-panels + split-bf16 MFMA -> out (r16 stage-2)

#define NREG 256   // N
#define KG   16    // gaussian kernels
#define MF   8     // features

typedef unsigned short u16;
typedef __attribute__((ext_vector_type(8))) short short8;   // 8 bf16 = 4 VGPR
typedef __attribute__((ext_vector_type(4))) float f32x4;

__device__ __forceinline__ void async_copy16(const void* g, void* l) {
    __builtin_amdgcn_global_load_lds(
        (const __attribute__((address_space(1))) void*)g,
        (__attribute__((address_space(3))) void*)l,
        16, 0, 0);
}

// inline-asm 16B global load: compiler must issue the batch where written.
__device__ __forceinline__ f32x4 ld16(const float* p) {
    f32x4 d;
    asm volatile("global_load_dwordx4 %0, %1, off" : "=v"(d) : "v"(p));
    return d;
}

__device__ __forceinline__ u16 bf16_rne(float x) {
    unsigned u = __float_as_uint(x);
    return (u16)((u + 0x7FFFu + ((u >> 16) & 1u)) >> 16);
}
__device__ __forceinline__ float bf16_to_f(u16 h) {
    return __uint_as_float(((unsigned)h) << 16);
}

__global__ __launch_bounds__(512, 1)
void k_all(const float* __restrict__ in,     // (16384, 256, 8)
           const float* __restrict__ kern,   // (256, 256, 16)
           const float* __restrict__ Wfeat,  // (1, 8)
           const float* __restrict__ Wlin,   // (1, 16)
           float* __restrict__ B,            // ws: 256x256
           float* __restrict__ Einv,         // ws: 256
           u16* __restrict__ Mh,             // ws: 256x256
           u16* __restrict__ Ml,             // ws: 256x256
           float* __restrict__ out) {        // (16384, 256)
    __shared__ __align__(16) u16 Ah[64 * 256];       // 32 KB
    __shared__ __align__(16) u16 Al[64 * 256];       // 32 KB
    __shared__ __align__(16) u16 Bh[256 * 64];       // 32 KB
    __shared__ __align__(16) u16 Bl[256 * 64];       // 32 KB
    __shared__ float red[NREG];                      // 1 KB (phase 1)
    __shared__ float rB[NREG], rP[NREG];             // 2 KB (phase 2)
    __shared__ float part[2][NREG];                  // 2 KB (phase 2)
    __shared__ float sden;

    const int tid = threadIdx.x, lane = tid & 63, wid = tid >> 6;  // wid 0..7
    const int b = blockIdx.x;            // block = B/M row index AND t-tile
    const int j = tid & 255;             // column 0..255
    const int h = tid >> 8;              // half 0/1
    cg::grid_group grid = cg::this_grid();

    // ================= phase 1: B row b, Einv[b] =================
    float km = 0.f;
    if (h == 0) {
        const float* kp = kern + ((size_t)b * NREG + j) * KG;
        float4 w0 = *(const float4*)(Wlin + 0);
        float4 w1 = *(const float4*)(Wlin + 4);
        float4 w2 = *(const float4*)(Wlin + 8);
        float4 w3 = *(const float4*)(Wlin + 12);
        float4 v0 = *(const float4*)(kp + 0);
        float4 v1 = *(const float4*)(kp + 4);
        float4 v2 = *(const float4*)(kp + 8);
        float4 v3 = *(const float4*)(kp + 12);
        km = v0.x*w0.x + v0.y*w0.y + v0.z*w0.z + v0.w*w0.w
           + v1.x*w1.x + v1.y*w1.y + v1.z*w1.z + v1.w*w1.w
           + v2.x*w2.x + v2.y*w2.y + v2.z*w2.z + v2.w*w2.w
           + v3.x*w3.x + v3.y*w3.y + v3.z*w3.z + v3.w*w3.w;
        red[j] = km;
    }
    __syncthreads();
    for (int s = 128; s > 0; s >>= 1) {
        if (h == 0 && j < s) red[j] += red[j + s];
        __syncthreads();
    }
    if (tid == 0) {
        float fw = 0.f;
#pragma unroll
        for (int m = 0; m < MF; ++m) fw += Wfeat[m];
        float den = fw + 2.f * red[0];
        sden = den;
        Einv[b] = 1.f / den;
    }
    __syncthreads();
    if (h == 0) B[(size_t)b * NREG + j] = 2.f * km / sden;

    grid.sync();   // ---- all B rows + Einv visible ----

    // ================= phase 2: M row b -> Mh/Ml =================
    {
        const int l0 = h * 128;
        if (h == 0) rB[j] = B[(size_t)b * NREG + j];
        __syncthreads();

#define ROWMM(rowv, dst_write)                                                \
    {                                                                         \
        float acc = 0.f;                                                      \
        _Pragma("unroll 4")                                                   \
        for (int l = l0; l < l0 + 128; l += 8) {                              \
            float b0 = B[(size_t)(l + 0) * NREG + j];                         \
            float b1 = B[(size_t)(l + 1) * NREG + j];                         \
            float b2 = B[(size_t)(l + 2) * NREG + j];                         \
            float b3 = B[(size_t)(l + 3) * NREG + j];                         \
            float b4 = B[(size_t)(l + 4) * NREG + j];                         \
            float b5 = B[(size_t)(l + 5) * NREG + j];                         \
            float b6 = B[(size_t)(l + 6) * NREG + j];                         \
            float b7 = B[(size_t)(l + 7) * NREG + j];                         \
            acc += rowv[l+0]*b0 + rowv[l+1]*b1 + rowv[l+2]*b2 + rowv[l+3]*b3  \
                 + rowv[l+4]*b4 + rowv[l+5]*b5 + rowv[l+6]*b6 + rowv[l+7]*b7; \
        }                                                                     \
        part[h][j] = acc;                                                     \
        __syncthreads();                                                      \
        dst_write                                                             \
        __syncthreads();                                                      \
    }

        float b2v = 0.f, b3v = 0.f, b4v = 0.f;
        ROWMM(rB,  { b2v = part[0][j] + part[1][j]; if (h == 0) rP[j] = b2v; })
        ROWMM(rP,  { b3v = part[0][j] + part[1][j]; if (h == 1) rP[j] = b3v; })
        ROWMM(rP,  { b4v = part[0][j] + part[1][j]; })

        if (h == 0) {
            const size_t idx = (size_t)b * NREG + j;
            float v = ((b == j) ? 1.f : 0.f) + rB[j] + b2v + b3v;
            v = v * Einv[j] + b4v;
            u16 hh = bf16_rne(v);
            Mh[idx] = hh;
            Ml[idx] = bf16_rne(v - bf16_to_f(hh));
        }
    }
    // NO grid sync here: stage-1 stream doesn't need M; sync moved after it.

    // ================= phase 3a: stream input tile (r16 stage-1) ==========
    const size_t t0 = (size_t)b * 64;
    float4 wa = *(const float4*)(Wfeat);
    float4 wb = *(const float4*)(Wfeat + 4);
    asm volatile("" :: "v"(wa.x), "v"(wa.y), "v"(wa.z), "v"(wa.w),
                       "v"(wb.x), "v"(wb.y), "v"(wb.z), "v"(wb.w));

    const float* rowbase = in + (t0 + wid * 8) * (NREG * MF);

#define ISSUE(BUF, TL)                                                        \
    {                                                                         \
        const float* rp_ = rowbase + (TL) * 2048 + lane * 8;                  \
        _Pragma("unroll")                                                     \
        for (int q = 0; q < 8; ++q)                                           \
            BUF[q] = ld16(rp_ + (q >> 1) * 512 + (q & 1) * 4);                \
    }

#define PROCESS(BUF, TL)                                                      \
    {                                                                         \
        const int t_ = wid * 8 + (TL);                                        \
        _Pragma("unroll")                                                     \
        for (int dq = 0; dq < 4; ++dq) {                                      \
            f32x4 a0 = BUF[2 * dq], a1 = BUF[2 * dq + 1];                     \
            float o = a0[0]*wa.x + a0[1]*wa.y + a0[2]*wa.z + a0[3]*wa.w       \
                    + a1[0]*wb.x + a1[1]*wb.y + a1[2]*wb.z + a1[3]*wb.w;      \
            u16 h_ = bf16_rne(o);                                             \
            u16 l_ = bf16_rne(o - bf16_to_f(h_));                             \
            const int j_ = dq * 64 + lane;                                    \
            const int idx_ = t_ * 256 + (((j_ >> 3) ^ (TL)) * 8) + (j_ & 7);  \
            Ah[idx_] = h_;                                                    \
            Al[idx_] = l_;                                                    \
        }                                                                     \
    }

#define WAITV(N)  asm volatile("s_waitcnt vmcnt(" #N ")" ::: "memory");       \
                  __builtin_amdgcn_sched_barrier(0);

    f32x4 ba[8], bb[8];
    ISSUE(ba, 0)
    ISSUE(bb, 1)
    WAITV(8)  PROCESS(ba, 0)  ISSUE(ba, 2)
    WAITV(8)  PROCESS(bb, 1)  ISSUE(bb, 3)
    WAITV(8)  PROCESS(ba, 2)  ISSUE(ba, 4)
    WAITV(8)  PROCESS(bb, 3)  ISSUE(bb, 5)
    WAITV(8)  PROCESS(ba, 4)  ISSUE(ba, 6)
    WAITV(8)  PROCESS(bb, 5)  ISSUE(bb, 7)
    WAITV(8)  PROCESS(ba, 6)
    WAITV(0)  PROCESS(bb, 7)

    __syncthreads();   // A splits resident (block-local)
    grid.sync();       // ---- all M rows visible; stragglers hidden ----

    // ================= phase 3b: 4 K-panels MFMA (r16 stage-2) ============
    const int m  = wid >> 1;
    const int nh = (wid & 1) * 8;
    const int mrow = m * 16 + (lane & 15);
    f32x4 acc[8];
#pragma unroll
    for (int n = 0; n < 8; ++n) acc[n] = (f32x4){0.f, 0.f, 0.f, 0.f};

    for (int p = 0; p < 4; ++p) {
        if (p) __syncthreads();      // previous panel fully consumed
#pragma unroll
        for (int s = 0; s < 8; ++s) {
            const int g = s * 8 + wid;              // 0..63
            const int i0 = (g & 31) * 8;
            const u16* sg = (g >> 5) ? Ml : Mh;
            u16* dg = (g >> 5) ? Bl : Bh;
            const int irow = i0 + (lane >> 3);
            const int ch = (lane & 7) ^ (lane >> 3);
            async_copy16(sg + (size_t)irow * NREG + p * 64 + ch * 8,
                         dg + i0 * 64);
        }
        __syncthreads();             // drains vmcnt -> panel resident

#pragma unroll
        for (int kst = 0; kst < 2; ++kst) {
            const int achunk = (8 * p + 4 * kst + (lane >> 4)) ^ (lane & 7);
            short8 a_h = *(const short8*)(Ah + mrow * 256 + achunk * 8);
            short8 a_l = *(const short8*)(Al + mrow * 256 + achunk * 8);
#pragma unroll
            for (int n = 0; n < 8; ++n) {
                const int irow = (nh + n) * 16 + (lane & 15);
                const int bchunk = (4 * kst + (lane >> 4)) ^ (lane & 7);
                short8 b_h = *(const short8*)(Bh + irow * 64 + bchunk * 8);
                short8 b_l = *(const short8*)(Bl + irow * 64 + bchunk * 8);
                acc[n] = __builtin_amdgcn_mfma_f32_16x16x32_bf16(a_h, b_h, acc[n], 0, 0, 0);
                acc[n] = __builtin_amdgcn_mfma_f32_16x16x32_bf16(a_h, b_l, acc[n], 0, 0, 0);
                acc[n] = __builtin_amdgcn_mfma_f32_16x16x32_bf16(a_l, b_h, acc[n], 0, 0, 0);
            }
        }
    }

    // ---- epilogue: D col = lane&15 (i), row = (lane>>4)*4 + reg (t)
    const size_t tbase = t0 + m * 16 + (lane >> 4) * 4;
#pragma unroll
    for (int n = 0; n < 8; ++n) {
#pragma unroll
        for (int r = 0; r < 4; ++r) {
            out[(tbase + r) * NREG + (nh + n) * 16 + (lane & 15)] = acc[n][r];
        }
    }
}

extern "C" void kernel_launch(void* const* d_in, const int* in_sizes, int n_in,
                              void* d_out, int out_size, void* d_ws, size_t ws_size,
                              hipStream_t stream) {
    const float* inputs  = (const float*)d_in[0];  // (16384, 256, 8)
    const float* kernels = (const float*)d_in[1];  // (256, 256, 16)
    const float* Wfeat   = (const float*)d_in[2];  // (1, 8)
    const float* Wlin    = (const float*)d_in[3];  // (1, 16)
    float* out = (float*)d_out;                    // (16384, 256)

    float* ws   = (float*)d_ws;                    // ~520 KB
    float* B    = ws;                              // 65536 f
    float* Einv = B + NREG * NREG;                 // 256 f
    u16*   Mh   = (u16*)(Einv + NREG);             // 65536 u16 (16B-aligned)
    u16*   Ml   = Mh + NREG * NREG;                // 65536 u16

    void* args[] = {
        (void*)&inputs, (void*)&kernels, (void*)&Wfeat, (void*)&Wlin,
        (void*)&B, (void*)&Einv, (void*)&Mh, (void*)&Ml, (void*)&out
    };
    hipLaunchCooperativeKernel((void*)k_all, dim3(256), dim3(512),
                               args, 0, stream);
}

// Round 19
// 49.186 us; speedup vs baseline: 2.3078x; 2.3078x over previous
//
#include <hip/hip_runtime.h>

// CRF-RNN collapsed: out[t,i] = sum_j M[i,j] * orig[t,j],
//   orig[t,j] = sum_m inputs[t,j,m]*W_feat[m]
//   M = (I + B + B^2 + B^3) * diag(1/denom) + B^4
// 3 dispatches (r16 structure; stage-1 pipeline deepened 2->3 rows):
//   k_prep -> B (fp32), Einv
//   k_rows -> per-row power chain (B L2-resident) -> Mh/Ml row
//   k_main -> direct global->VGPR stream (3-row rotation, 24 loads in
//             flight/wave, vmcnt(16)) + 4 B-panel split-bf16 MFMA

#define NREG 256   // N
#define KG   16    // gaussian kernels
#define MF   8     // features

typedef unsigned short u16;
typedef __attribute__((ext_vector_type(8))) short short8;   // 8 bf16 = 4 VGPR
typedef __attribute__((ext_vector_type(4))) float f32x4;

__device__ __forceinline__ void async_copy16(const void* g, void* l) {
    __builtin_amdgcn_global_load_lds(
        (const __attribute__((address_space(1))) void*)g,
        (__attribute__((address_space(3))) void*)l,
        16, 0, 0);
}

// inline-asm 16B global load: compiler must issue the batch where written.
__device__ __forceinline__ f32x4 ld16(const float* p) {
    f32x4 d;
    asm volatile("global_load_dwordx4 %0, %1, off" : "=v"(d) : "v"(p));
    return d;
}

__device__ __forceinline__ u16 bf16_rne(float x) {
    unsigned u = __float_as_uint(x);
    return (u16)((u + 0x7FFFu + ((u >> 16) & 1u)) >> 16);
}
__device__ __forceinline__ float bf16_to_f(u16 h) {
    return __uint_as_float(((unsigned)h) << 16);
}

// ---------------- K1: Kmat row, denom, B, Einv ----------------
__global__ __launch_bounds__(256) void k_prep(const float* __restrict__ kern,
                                              const float* __restrict__ Wlin,
                                              const float* __restrict__ Wfeat,
                                              float* __restrict__ B,
                                              float* __restrict__ Einv) {
    const int i = blockIdx.x, j = threadIdx.x;
    const float* kp = kern + ((size_t)i * NREG + j) * KG;
    float4 w0 = *(const float4*)(Wlin + 0);
    float4 w1 = *(const float4*)(Wlin + 4);
    float4 w2 = *(const float4*)(Wlin + 8);
    float4 w3 = *(const float4*)(Wlin + 12);
    float4 v0 = *(const float4*)(kp + 0);
    float4 v1 = *(const float4*)(kp + 4);
    float4 v2 = *(const float4*)(kp + 8);
    float4 v3 = *(const float4*)(kp + 12);
    float km = v0.x*w0.x + v0.y*w0.y + v0.z*w0.z + v0.w*w0.w
             + v1.x*w1.x + v1.y*w1.y + v1.z*w1.z + v1.w*w1.w
             + v2.x*w2.x + v2.y*w2.y + v2.z*w2.z + v2.w*w2.w
             + v3.x*w3.x + v3.y*w3.y + v3.z*w3.z + v3.w*w3.w;

    __shared__ float red[256];
    red[j] = km;
    __syncthreads();
    for (int s = 128; s > 0; s >>= 1) {
        if (j < s) red[j] += red[j + s];
        __syncthreads();
    }
    __shared__ float sden;
    if (j == 0) {
        float fw = 0.f;
#pragma unroll
        for (int m = 0; m < MF; ++m) fw += Wfeat[m];
        float den = fw + 2.f * red[0];
        sden = den;
        Einv[i] = 1.f / den;
    }
    __syncthreads();
    B[(size_t)i * NREG + j] = 2.f * km / sden;
}

// ---------------- K2: full power-chain per row -> Mh/Ml --------------------
__global__ __launch_bounds__(512) void k_rows(const float* __restrict__ B,
                                              const float* __restrict__ Einv,
                                              u16* __restrict__ Mh,
                                              u16* __restrict__ Ml) {
    const int i = blockIdx.x;
    const int j = threadIdx.x & 255;
    const int h = threadIdx.x >> 8;       // 0/1: l-half
    const int l0 = h * 128;
    __shared__ float rB[NREG], rP[NREG];
    __shared__ float part[2][NREG];

    if (h == 0) rB[j] = B[(size_t)i * NREG + j];
    __syncthreads();

#define ROWMM(rowv, dst_write)                                                \
    {                                                                         \
        float acc = 0.f;                                                      \
        _Pragma("unroll 4")                                                   \
        for (int l = l0; l < l0 + 128; l += 8) {                              \
            float b0 = B[(size_t)(l + 0) * NREG + j];                         \
            float b1 = B[(size_t)(l + 1) * NREG + j];                         \
            float b2 = B[(size_t)(l + 2) * NREG + j];                         \
            float b3 = B[(size_t)(l + 3) * NREG + j];                         \
            float b4 = B[(size_t)(l + 4) * NREG + j];                         \
            float b5 = B[(size_t)(l + 5) * NREG + j];                         \
            float b6 = B[(size_t)(l + 6) * NREG + j];                         \
            float b7 = B[(size_t)(l + 7) * NREG + j];                         \
            acc += rowv[l+0]*b0 + rowv[l+1]*b1 + rowv[l+2]*b2 + rowv[l+3]*b3  \
                 + rowv[l+4]*b4 + rowv[l+5]*b5 + rowv[l+6]*b6 + rowv[l+7]*b7; \
        }                                                                     \
        part[h][j] = acc;                                                     \
        __syncthreads();                                                      \
        dst_write                                                             \
        __syncthreads();                                                      \
    }

    float b2v = 0.f, b3v = 0.f, b4v = 0.f;
    ROWMM(rB,  { b2v = part[0][j] + part[1][j]; if (h == 0) rP[j] = b2v; })
    ROWMM(rP,  { b3v = part[0][j] + part[1][j]; if (h == 1) rP[j] = b3v; })
    ROWMM(rP,  { b4v = part[0][j] + part[1][j]; })

    if (h == 0) {
        const size_t idx = (size_t)i * NREG + j;
        float v = ((i == j) ? 1.f : 0.f) + rB[j] + b2v + b3v;
        v = v * Einv[j] + b4v;
        u16 hh = bf16_rne(v);
        Mh[idx] = hh;
        Ml[idx] = bf16_rne(v - bf16_to_f(hh));
    }
}

// ---------------- K3: fused feature-reduce + MFMA GEMM ---------------------
// Block = 512 thr (8 waves), 64 t-rows; grid 256 (1 block/CU).
// Stage 1: direct global->VGPR stream, inline-asm batched loads, 3-row
//   rotation (24 loads = 3 KB in flight per wave), counted vmcnt(16).
// Stage 2 (r9/r16-verified, byte-identical): 4 K-panels of 64 j via
//   global_load_lds, split-bf16, 3 MFMA products.
__global__ __launch_bounds__(512, 1) void k_main(const float* __restrict__ in,
                                                 const float* __restrict__ Wfeat,
                                                 const u16* __restrict__ Mh,
                                                 const u16* __restrict__ Ml,
                                                 float* __restrict__ out) {
    __shared__ __align__(16) u16 Ah[64 * 256];       // 32 KB
    __shared__ __align__(16) u16 Al[64 * 256];       // 32 KB
    __shared__ __align__(16) u16 Bh[256 * 64];       // 32 KB
    __shared__ __align__(16) u16 Bl[256 * 64];       // 32 KB

    const int tid = threadIdx.x, lane = tid & 63, wid = tid >> 6;  // wid 0..7
    const size_t t0 = (size_t)blockIdx.x * 64;

    float4 wa = *(const float4*)(Wfeat);
    float4 wb = *(const float4*)(Wfeat + 4);
    asm volatile("" :: "v"(wa.x), "v"(wa.y), "v"(wa.z), "v"(wa.w),
                       "v"(wb.x), "v"(wb.y), "v"(wb.z), "v"(wb.w));

    // ---- stage 1: 8 rows/wave, 3-row rotation ----
    const float* rowbase = in + (t0 + wid * 8) * (NREG * MF);

#define ISSUE(BUF, TL)                                                        \
    {                                                                         \
        const float* rp_ = rowbase + (TL) * 2048 + lane * 8;                  \
        _Pragma("unroll")                                                     \
        for (int q = 0; q < 8; ++q)                                           \
            BUF[q] = ld16(rp_ + (q >> 1) * 512 + (q & 1) * 4);                \
    }

#define PROCESS(BUF, TL)                                                      \
    {                                                                         \
        const int t_ = wid * 8 + (TL);                                        \
        _Pragma("unroll")                                                     \
        for (int dq = 0; dq < 4; ++dq) {                                      \
            f32x4 a0 = BUF[2 * dq], a1 = BUF[2 * dq + 1];                     \
            float o = a0[0]*wa.x + a0[1]*wa.y + a0[2]*wa.z + a0[3]*wa.w       \
                    + a1[0]*wb.x + a1[1]*wb.y + a1[2]*wb.z + a1[3]*wb.w;      \
            u16 h_ = bf16_rne(o);                                             \
            u16 l_ = bf16_rne(o - bf16_to_f(h_));                             \
            const int j_ = dq * 64 + lane;                                    \
            const int idx_ = t_ * 256 + (((j_ >> 3) ^ (TL)) * 8) + (j_ & 7);  \
            Ah[idx_] = h_;                                                    \
            Al[idx_] = l_;                                                    \
        }                                                                     \
    }

#define WAITV(N)  asm volatile("s_waitcnt vmcnt(" #N ")" ::: "memory");       \
                  __builtin_amdgcn_sched_barrier(0);

    f32x4 ba[8], bb[8], bc[8];
    ISSUE(ba, 0)
    ISSUE(bb, 1)
    ISSUE(bc, 2)
    WAITV(16)  PROCESS(ba, 0)  ISSUE(ba, 3)
    WAITV(16)  PROCESS(bb, 1)  ISSUE(bb, 4)
    WAITV(16)  PROCESS(bc, 2)  ISSUE(bc, 5)
    WAITV(16)  PROCESS(ba, 3)  ISSUE(ba, 6)
    WAITV(16)  PROCESS(bb, 4)  ISSUE(bb, 7)
    WAITV(16)  PROCESS(bc, 5)
    WAITV(8)   PROCESS(ba, 6)
    WAITV(0)   PROCESS(bb, 7)

    __syncthreads();   // A splits resident

    // ---- stage 2: 4 K-panels of 64 j. Wave w: m-tile w>>1, n-half w&1.
    const int mrow = (wid >> 1) * 16 + (lane & 15);
    const int nh   = (wid & 1) * 8;
    f32x4 acc[8];
#pragma unroll
    for (int n = 0; n < 8; ++n) acc[n] = (f32x4){0.f, 0.f, 0.f, 0.f};

    for (int p = 0; p < 4; ++p) {
        if (p) __syncthreads();      // previous panel fully consumed
#pragma unroll
        for (int s = 0; s < 8; ++s) {
            const int g = s * 8 + wid;              // 0..63
            const int i0 = (g & 31) * 8;
            const u16* sg = (g >> 5) ? Ml : Mh;
            u16* dg = (g >> 5) ? Bl : Bh;
            const int irow = i0 + (lane >> 3);
            const int ch = (lane & 7) ^ (lane >> 3);
            async_copy16(sg + (size_t)irow * NREG + p * 64 + ch * 8,
                         dg + i0 * 64);
        }
        __syncthreads();             // drains vmcnt -> panel resident

#pragma unroll
        for (int kst = 0; kst < 2; ++kst) {
            const int achunk = (8 * p + 4 * kst + (lane >> 4)) ^ (lane & 7);
            short8 a_h = *(const short8*)(Ah + mrow * 256 + achunk * 8);
            short8 a_l = *(const short8*)(Al + mrow * 256 + achunk * 8);
#pragma unroll
            for (int n = 0; n < 8; ++n) {
                const int irow = (nh + n) * 16 + (lane & 15);
                const int bchunk = (4 * kst + (lane >> 4)) ^ (lane & 7);
                short8 b_h = *(const short8*)(Bh + irow * 64 + bchunk * 8);
                short8 b_l = *(const short8*)(Bl + irow * 64 + bchunk * 8);
                acc[n] = __builtin_amdgcn_mfma_f32_16x16x32_bf16(a_h, b_h, acc[n], 0, 0, 0);
                acc[n] = __builtin_amdgcn_mfma_f32_16x16x32_bf16(a_h, b_l, acc[n], 0, 0, 0);
                acc[n] = __builtin_amdgcn_mfma_f32_16x16x32_bf16(a_l, b_h, acc[n], 0, 0, 0);
            }
        }
    }

    // ---- epilogue: D col = lane&15 (i), row = (lane>>4)*4 + reg (t)
    const size_t tbase = t0 + (wid >> 1) * 16 + (lane >> 4) * 4;
#pragma unroll
    for (int n = 0; n < 8; ++n) {
#pragma unroll
        for (int r = 0; r < 4; ++r) {
            out[(tbase + r) * NREG + (nh + n) * 16 + (lane & 15)] = acc[n][r];
        }
    }
}

extern "C" void kernel_launch(void* const* d_in, const int* in_sizes, int n_in,
                              void* d_out, int out_size, void* d_ws, size_t ws_size,
                              hipStream_t stream) {
    const float* inputs  = (const float*)d_in[0];  // (16384, 256, 8)
    const float* kernels = (const float*)d_in[1];  // (256, 256, 16)
    const float* Wfeat   = (const float*)d_in[2];  // (1, 8)
    const float* Wlin    = (const float*)d_in[3];  // (1, 16)
    float* out = (float*)d_out;                    // (16384, 256)

    float* ws   = (float*)d_ws;                    // ~520 KB
    float* B    = ws;                              // 65536 f
    float* Einv = B + NREG * NREG;                 // 256 f
    u16*   Mh   = (u16*)(Einv + NREG);             // 65536 u16 (16B-aligned)
    u16*   Ml   = Mh + NREG * NREG;                // 65536 u16

    k_prep <<<256, 256, 0, stream>>>(kernels, Wlin, Wfeat, B, Einv);
    k_rows <<<256, 512, 0, stream>>>(B, Einv, Mh, Ml);
    k_main <<<256, 512, 0, stream>>>(inputs, Wfeat, Mh, Ml, out);
}

// Round 20
// 48.728 us; speedup vs baseline: 2.3295x; 1.0094x over previous
//
#include <hip/hip_runtime.h>

// CRF-RNN collapsed: out[t,i] = sum_j M[i,j] * orig[t,j],
//   orig[t,j] = sum_m inputs[t,j,m]*W_feat[m]
//   M = (I + B + B^2 + B^3) * diag(1/denom) + B^4
// 3 dispatches (r19 structure; stage-1 4-deep rotation; panel-0 B staging
// hoisted under the stream):
//   k_prep -> B (fp32), Einv
//   k_rows -> per-row power chain (B L2-resident) -> Mh/Ml row
//   k_main -> direct global->VGPR stream (32 loads in flight/wave,
//             vmcnt(24)) + 4 B-panel split-bf16 MFMA (panel 0 prefetched)

#define NREG 256   // N
#define KG   16    // gaussian kernels
#define MF   8     // features

typedef unsigned short u16;
typedef __attribute__((ext_vector_type(8))) short short8;   // 8 bf16 = 4 VGPR
typedef __attribute__((ext_vector_type(4))) float f32x4;

__device__ __forceinline__ void async_copy16(const void* g, void* l) {
    __builtin_amdgcn_global_load_lds(
        (const __attribute__((address_space(1))) void*)g,
        (__attribute__((address_space(3))) void*)l,
        16, 0, 0);
}

// inline-asm 16B global load: compiler must issue the batch where written.
__device__ __forceinline__ f32x4 ld16(const float* p) {
    f32x4 d;
    asm volatile("global_load_dwordx4 %0, %1, off" : "=v"(d) : "v"(p));
    return d;
}

__device__ __forceinline__ u16 bf16_rne(float x) {
    unsigned u = __float_as_uint(x);
    return (u16)((u + 0x7FFFu + ((u >> 16) & 1u)) >> 16);
}
__device__ __forceinline__ float bf16_to_f(u16 h) {
    return __uint_as_float(((unsigned)h) << 16);
}

// ---------------- K1: Kmat row, denom, B, Einv ----------------
__global__ __launch_bounds__(256) void k_prep(const float* __restrict__ kern,
                                              const float* __restrict__ Wlin,
                                              const float* __restrict__ Wfeat,
                                              float* __restrict__ B,
                                              float* __restrict__ Einv) {
    const int i = blockIdx.x, j = threadIdx.x;
    const float* kp = kern + ((size_t)i * NREG + j) * KG;
    float4 w0 = *(const float4*)(Wlin + 0);
    float4 w1 = *(const float4*)(Wlin + 4);
    float4 w2 = *(const float4*)(Wlin + 8);
    float4 w3 = *(const float4*)(Wlin + 12);
    float4 v0 = *(const float4*)(kp + 0);
    float4 v1 = *(const float4*)(kp + 4);
    float4 v2 = *(const float4*)(kp + 8);
    float4 v3 = *(const float4*)(kp + 12);
    float km = v0.x*w0.x + v0.y*w0.y + v0.z*w0.z + v0.w*w0.w
             + v1.x*w1.x + v1.y*w1.y + v1.z*w1.z + v1.w*w1.w
             + v2.x*w2.x + v2.y*w2.y + v2.z*w2.z + v2.w*w2.w
             + v3.x*w3.x + v3.y*w3.y + v3.z*w3.z + v3.w*w3.w;

    __shared__ float red[256];
    red[j] = km;
    __syncthreads();
    for (int s = 128; s > 0; s >>= 1) {
        if (j < s) red[j] += red[j + s];
        __syncthreads();
    }
    __shared__ float sden;
    if (j == 0) {
        float fw = 0.f;
#pragma unroll
        for (int m = 0; m < MF; ++m) fw += Wfeat[m];
        float den = fw + 2.f * red[0];
        sden = den;
        Einv[i] = 1.f / den;
    }
    __syncthreads();
    B[(size_t)i * NREG + j] = 2.f * km / sden;
}

// ---------------- K2: full power-chain per row -> Mh/Ml --------------------
__global__ __launch_bounds__(512) void k_rows(const float* __restrict__ B,
                                              const float* __restrict__ Einv,
                                              u16* __restrict__ Mh,
                                              u16* __restrict__ Ml) {
    const int i = blockIdx.x;
    const int j = threadIdx.x & 255;
    const int h = threadIdx.x >> 8;       // 0/1: l-half
    const int l0 = h * 128;
    __shared__ float rB[NREG], rP[NREG];
    __shared__ float part[2][NREG];

    if (h == 0) rB[j] = B[(size_t)i * NREG + j];
    __syncthreads();

#define ROWMM(rowv, dst_write)                                                \
    {                                                                         \
        float acc = 0.f;                                                      \
        _Pragma("unroll 4")                                                   \
        for (int l = l0; l < l0 + 128; l += 8) {                              \
            float b0 = B[(size_t)(l + 0) * NREG + j];                         \
            float b1 = B[(size_t)(l + 1) * NREG + j];                         \
            float b2 = B[(size_t)(l + 2) * NREG + j];                         \
            float b3 = B[(size_t)(l + 3) * NREG + j];                         \
            float b4 = B[(size_t)(l + 4) * NREG + j];                         \
            float b5 = B[(size_t)(l + 5) * NREG + j];                         \
            float b6 = B[(size_t)(l + 6) * NREG + j];                         \
            float b7 = B[(size_t)(l + 7) * NREG + j];                         \
            acc += rowv[l+0]*b0 + rowv[l+1]*b1 + rowv[l+2]*b2 + rowv[l+3]*b3  \
                 + rowv[l+4]*b4 + rowv[l+5]*b5 + rowv[l+6]*b6 + rowv[l+7]*b7; \
        }                                                                     \
        part[h][j] = acc;                                                     \
        __syncthreads();                                                      \
        dst_write                                                             \
        __syncthreads();                                                      \
    }

    float b2v = 0.f, b3v = 0.f, b4v = 0.f;
    ROWMM(rB,  { b2v = part[0][j] + part[1][j]; if (h == 0) rP[j] = b2v; })
    ROWMM(rP,  { b3v = part[0][j] + part[1][j]; if (h == 1) rP[j] = b3v; })
    ROWMM(rP,  { b4v = part[0][j] + part[1][j]; })

    if (h == 0) {
        const size_t idx = (size_t)i * NREG + j;
        float v = ((i == j) ? 1.f : 0.f) + rB[j] + b2v + b3v;
        v = v * Einv[j] + b4v;
        u16 hh = bf16_rne(v);
        Mh[idx] = hh;
        Ml[idx] = bf16_rne(v - bf16_to_f(hh));
    }
}

// ---------------- K3: fused feature-reduce + MFMA GEMM ---------------------
// Block = 512 thr (8 waves), 64 t-rows; grid 256 (1 block/CU).
// Stage 1: direct global->VGPR stream, inline-asm batched loads, 4-row
//   rotation (32 loads = 4 KB in flight per wave), counted vmcnt(24).
//   Panel-0 B staging issued BEFORE the stream (vmcnt retires in order, so
//   the counted waits are prefix-invariant); its latency hides under the
//   stream and the stage-1 barrier drain makes it resident for free.
// Stage 2: MFMA-first loop; panels 1..3 staged between 2 barriers (verified
//   r16 mapping). Split-bf16, 3 MFMA products.
__global__ __launch_bounds__(512, 1) void k_main(const float* __restrict__ in,
                                                 const float* __restrict__ Wfeat,
                                                 const u16* __restrict__ Mh,
                                                 const u16* __restrict__ Ml,
                                                 float* __restrict__ out) {
    __shared__ __align__(16) u16 Ah[64 * 256];       // 32 KB
    __shared__ __align__(16) u16 Al[64 * 256];       // 32 KB
    __shared__ __align__(16) u16 Bh[256 * 64];       // 32 KB
    __shared__ __align__(16) u16 Bl[256 * 64];       // 32 KB

    const int tid = threadIdx.x, lane = tid & 63, wid = tid >> 6;  // wid 0..7
    const size_t t0 = (size_t)blockIdx.x * 64;

    float4 wa = *(const float4*)(Wfeat);
    float4 wb = *(const float4*)(Wfeat + 4);
    asm volatile("" :: "v"(wa.x), "v"(wa.y), "v"(wa.z), "v"(wa.w),
                       "v"(wb.x), "v"(wb.y), "v"(wb.z), "v"(wb.w));

    // stage B panel P: 8 gll per wave (r9/r16-verified mapping);
    // dest linear; source pre-swizzled: src chunk = (lds chunk)^(irow&7)
#define STAGEB(P)                                                             \
    {                                                                         \
        _Pragma("unroll")                                                     \
        for (int s = 0; s < 8; ++s) {                                         \
            const int g = s * 8 + wid;              /* 0..63 */               \
            const int i0 = (g & 31) * 8;                                      \
            const u16* sg = (g >> 5) ? Ml : Mh;                               \
            u16* dg = (g >> 5) ? Bl : Bh;                                     \
            const int irow = i0 + (lane >> 3);                                \
            const int ch = (lane & 7) ^ (lane >> 3);                          \
            async_copy16(sg + (size_t)irow * NREG + (P) * 64 + ch * 8,        \
                         dg + i0 * 64);                                       \
        }                                                                     \
    }

    // panel 0 prefetch: issued before the stream; retires first (in-order)
    STAGEB(0)

    // ---- stage 1: 8 rows/wave, 4-row rotation ----
    const float* rowbase = in + (t0 + wid * 8) * (NREG * MF);

#define ISSUE(BUF, TL)                                                        \
    {                                                                         \
        const float* rp_ = rowbase + (TL) * 2048 + lane * 8;                  \
        _Pragma("unroll")                                                     \
        for (int q = 0; q < 8; ++q)                                           \
            BUF[q] = ld16(rp_ + (q >> 1) * 512 + (q & 1) * 4);                \
    }

#define PROCESS(BUF, TL)                                                      \
    {                                                                         \
        const int t_ = wid * 8 + (TL);                                        \
        _Pragma("unroll")                                                     \
        for (int dq = 0; dq < 4; ++dq) {                                      \
            f32x4 a0 = BUF[2 * dq], a1 = BUF[2 * dq + 1];                     \
            float o = a0[0]*wa.x + a0[1]*wa.y + a0[2]*wa.z + a0[3]*wa.w       \
                    + a1[0]*wb.x + a1[1]*wb.y + a1[2]*wb.z + a1[3]*wb.w;      \
            u16 h_ = bf16_rne(o);                                             \
            u16 l_ = bf16_rne(o - bf16_to_f(h_));                             \
            const int j_ = dq * 64 + lane;                                    \
            const int idx_ = t_ * 256 + (((j_ >> 3) ^ (TL)) * 8) + (j_ & 7);  \
            Ah[idx_] = h_;                                                    \
            Al[idx_] = l_;                                                    \
        }                                                                     \
    }

#define WAITV(N)  asm volatile("s_waitcnt vmcnt(" #N ")" ::: "memory");       \
                  __builtin_amdgcn_sched_barrier(0);

    f32x4 ba[8], bb[8], bc[8], bd[8];
    ISSUE(ba, 0)
    ISSUE(bb, 1)
    ISSUE(bc, 2)
    ISSUE(bd, 3)
    WAITV(24)  PROCESS(ba, 0)  ISSUE(ba, 4)
    WAITV(24)  PROCESS(bb, 1)  ISSUE(bb, 5)
    WAITV(24)  PROCESS(bc, 2)  ISSUE(bc, 6)
    WAITV(24)  PROCESS(bd, 3)  ISSUE(bd, 7)
    WAITV(24)  PROCESS(ba, 4)
    WAITV(16)  PROCESS(bb, 5)
    WAITV(8)   PROCESS(bc, 6)
    WAITV(0)   PROCESS(bd, 7)

    __syncthreads();   // drains vmcnt+lgkm: A splits AND panel 0 resident

    // ---- stage 2: MFMA-first; panels 1..3 staged between barriers.
    const int mrow = (wid >> 1) * 16 + (lane & 15);
    const int nh   = (wid & 1) * 8;
    f32x4 acc[8];
#pragma unroll
    for (int n = 0; n < 8; ++n) acc[n] = (f32x4){0.f, 0.f, 0.f, 0.f};

    for (int p = 0; p < 4; ++p) {
#pragma unroll
        for (int kst = 0; kst < 2; ++kst) {
            const int achunk = (8 * p + 4 * kst + (lane >> 4)) ^ (lane & 7);
            short8 a_h = *(const short8*)(Ah + mrow * 256 + achunk * 8);
            short8 a_l = *(const short8*)(Al + mrow * 256 + achunk * 8);
#pragma unroll
            for (int n = 0; n < 8; ++n) {
                const int irow = (nh + n) * 16 + (lane & 15);
                const int bchunk = (4 * kst + (lane >> 4)) ^ (lane & 7);
                short8 b_h = *(const short8*)(Bh + irow * 64 + bchunk * 8);
                short8 b_l = *(const short8*)(Bl + irow * 64 + bchunk * 8);
                acc[n] = __builtin_amdgcn_mfma_f32_16x16x32_bf16(a_h, b_h, acc[n], 0, 0, 0);
                acc[n] = __builtin_amdgcn_mfma_f32_16x16x32_bf16(a_h, b_l, acc[n], 0, 0, 0);
                acc[n] = __builtin_amdgcn_mfma_f32_16x16x32_bf16(a_l, b_h, acc[n], 0, 0, 0);
            }
        }
        if (p < 3) {
            __syncthreads();         // panel p fully consumed by all waves
            STAGEB(p + 1)
            __syncthreads();         // drains vmcnt -> panel p+1 resident
        }
    }

    // ---- epilogue: D col = lane&15 (i), row = (lane>>4)*4 + reg (t)
    const size_t tbase = t0 + (wid >> 1) * 16 + (lane >> 4) * 4;
#pragma unroll
    for (int n = 0; n < 8; ++n) {
#pragma unroll
        for (int r = 0; r < 4; ++r) {
            out[(tbase + r) * NREG + (nh + n) * 16 + (lane & 15)] = acc[n][r];
        }
    }
}

extern "C" void kernel_launch(void* const* d_in, const int* in_sizes, int n_in,
                              void* d_out, int out_size, void* d_ws, size_t ws_size,
                              hipStream_t stream) {
    const float* inputs  = (const float*)d_in[0];  // (16384, 256, 8)
    const float* kernels = (const float*)d_in[1];  // (256, 256, 16)
    const float* Wfeat   = (const float*)d_in[2];  // (1, 8)
    const float* Wlin    = (const float*)d_in[3];  // (1, 16)
    float* out = (float*)d_out;                    // (16384, 256)

    float* ws   = (float*)d_ws;                    // ~520 KB
    float* B    = ws;                              // 65536 f
    float* Einv = B + NREG * NREG;                 // 256 f
    u16*   Mh   = (u16*)(Einv + NREG);             // 65536 u16 (16B-aligned)
    u16*   Ml   = Mh + NREG * NREG;                // 65536 u16

    k_prep <<<256, 256, 0, stream>>>(kernels, Wlin, Wfeat, B, Einv);
    k_rows <<<256, 512, 0, stream>>>(B, Einv, Mh, Ml);
    k_main <<<256, 512, 0, stream>>>(inputs, Wfeat, Mh, Ml, out);
}